// Round 17
// baseline (73.188 us; speedup 1.0000x reference)
//
#include <hip/hip_runtime.h>
#include <stdint.h>

#define NBL 8
#define MBS 512
#define CIN 1024
#define UQ  1024

// ---- Cl(3,0) ~ M2(C) tables (HW-verified R11/R12) ----
__device__ __constant__ int   px_sA[4] = {0,1,4,2};
__device__ __constant__ int   px_sB[4] = {3,5,7,6};
__device__ __constant__ int   px_vA[4] = {0,1,4,5};
__device__ __constant__ float px_cA0[4] = {1,1,1,-1};
__device__ __constant__ float px_cA1[4] = {1,-1,1,1};
__device__ __constant__ int   px_vB[4] = {3,2,7,6};
__device__ __constant__ float px_cB0[4] = {1,1,-1,1};
__device__ __constant__ float px_cB1[4] = {-1,1,1,1};
__device__ __constant__ int c_sa[8][4] = {
  {0,8,1,9},{0,4,1,5},{0,8,1,9},{0,4,1,5},
  {2,10,3,11},{2,6,3,7},{2,10,3,11},{2,6,3,7}};
__device__ __constant__ int c_sb[8][4] = {
  {0,4,2,6},{4,0,6,2},{1,5,3,7},{5,1,7,3},
  {0,4,2,6},{4,0,6,2},{1,5,3,7},{5,1,7,3}};
// dest -> two blade outputs (atomic fallback path)
__device__ __constant__ int   c_eb0[8] = {0,4,1,2,1,2,0,4};
__device__ __constant__ float c_es0[8] = {1,1,1,-1,1,1,1,-1};
__device__ __constant__ int   c_eb1[8] = {3,7,5,6,5,6,3,7};
__device__ __constant__ float c_es1[8] = {1,1,-1,1,1,1,-1,1};

// original Cayley tables (naive fallback only)
__device__ __constant__ int c_sigma[8][8] = {
  {0,1,2,3,4,5,6,7},{1,0,4,5,2,3,7,6},{2,4,0,6,1,7,3,5},{3,5,6,0,7,1,2,4},
  {4,2,1,7,0,6,5,3},{5,3,7,1,6,0,4,2},{6,7,3,2,5,4,0,1},{7,6,5,4,3,2,1,0}};
__device__ __constant__ int c_sg[8][8] = {
  {1,1,1,1,1,1,1,1},{1,1,1,1,1,1,1,1},{1,-1,1,1,-1,-1,1,-1},{1,-1,-1,1,1,-1,-1,1},
  {-1,1,-1,-1,1,1,-1,1},{-1,1,1,-1,-1,1,1,-1},{-1,-1,1,-1,1,-1,1,1},{-1,-1,1,-1,1,-1,1,1}};

typedef short bf16x8 __attribute__((ext_vector_type(8)));
typedef float f32x4 __attribute__((ext_vector_type(4)));

__device__ __forceinline__ uint32_t f2bf(float f) {
  uint32_t u = __float_as_uint(f);
  return (u + 0x7fffu + ((u >> 16) & 1u)) >> 16;  // RNE
}
__device__ __forceinline__ uint32_t pk2(float lo, float hi) {
  return f2bf(lo) | (f2bf(hi) << 16);
}

// Xv[v 0..11][chunk 0..127][row 0..511][8] bf16, pair-shared sources.
__global__ void cvt_x_kernel(const float* __restrict__ x, uint4* __restrict__ xv) {
  __shared__ uint4 tA[32 * 33], tB[32 * 33];
  const int tid = threadIdx.x;           // 256
  const int tx = tid & 31, ty = tid >> 5;
  const int p  = blockIdx.x >> 2;        // pair 0..3
  const int cb = blockIdx.x & 3;
  const int m0 = blockIdx.y * 32;
  const int sA = px_sA[p] * MBS, sB = px_sB[p] * MBS;
  const float cA0 = px_cA0[p], cA1 = px_cA1[p];
  const float cB0 = px_cB0[p], cB1 = px_cB1[p];
#pragma unroll
  for (int r = 0; r < 4; ++r) {
    const int m = m0 + ty + r * 8;
    const float* pa = x + (size_t)(sA + m) * CIN + cb * 256 + tx * 8;
    const float* pb = x + (size_t)(sB + m) * CIN + cb * 256 + tx * 8;
    float4 a0 = *(const float4*)pa, a1 = *(const float4*)(pa + 4);
    float4 b0 = *(const float4*)pb, b1 = *(const float4*)(pb + 4);
    uint4 vA, vB;
    vA.x = pk2(cA0*a0.x + cA1*b0.x, cA0*a0.y + cA1*b0.y);
    vA.y = pk2(cA0*a0.z + cA1*b0.z, cA0*a0.w + cA1*b0.w);
    vA.z = pk2(cA0*a1.x + cA1*b1.x, cA0*a1.y + cA1*b1.y);
    vA.w = pk2(cA0*a1.z + cA1*b1.z, cA0*a1.w + cA1*b1.w);
    vB.x = pk2(cB0*a0.x + cB1*b0.x, cB0*a0.y + cB1*b0.y);
    vB.y = pk2(cB0*a0.z + cB1*b0.z, cB0*a0.w + cB1*b0.w);
    vB.z = pk2(cB0*a1.x + cB1*b1.x, cB0*a1.y + cB1*b1.y);
    vB.w = pk2(cB0*a1.z + cB1*b1.z, cB0*a1.w + cB1*b1.w);
    tA[tx * 33 + ty + r * 8] = vA;
    tB[tx * 33 + ty + r * 8] = vB;
  }
  __syncthreads();
  const int vA = px_vA[p], vB = px_vB[p];
#pragma unroll
  for (int ph = 0; ph < 4; ++ph) {
    const int slot = ph * 256 + tid;
    const int cc = slot >> 5, mm = slot & 31;
    const size_t off = (size_t)(cb * 32 + cc) * 512 + m0 + mm;
    uint4 a = tA[cc * 33 + mm];
    uint4 b = tB[cc * 33 + mm];
    xv[(size_t)vA * 65536 + off] = a;
    xv[(size_t)vB * 65536 + off] = b;
    if (p >= 2) {
      uint4 na, nb;
      na.x = a.x ^ 0x80008000u; na.y = a.y ^ 0x80008000u;
      na.z = a.z ^ 0x80008000u; na.w = a.w ^ 0x80008000u;
      nb.x = b.x ^ 0x80008000u; nb.y = b.y ^ 0x80008000u;
      nb.z = b.z ^ 0x80008000u; nb.w = b.w ^ 0x80008000u;
      xv[(size_t)(vA + 4) * 65536 + off] = na;
      xv[(size_t)(vB + 4) * 65536 + off] = nb;
    }
  }
}

// Wv[v 0..7][chunk 0..127][col 0..1023][8] bf16, scaled 0.5, pair-shared.
__global__ void cvt_w_kernel(const float* __restrict__ w, uint4* __restrict__ wv) {
  __shared__ float ta[32][65], tb[32][65];
  const int tid = threadIdx.x;  // 256
  const int tx = tid & 63, ty = tid >> 6;
  const int p  = blockIdx.x >> 4;
  const int nb = blockIdx.x & 15;
  const int k0 = blockIdx.y * 32;
  const int sAc = px_sA[p] * UQ + nb * 64;
  const int sBc = px_sB[p] * UQ + nb * 64;
#pragma unroll
  for (int r = 0; r < 8; ++r) {
    const int kr = ty * 8 + r;
    ta[kr][tx] = w[(size_t)(k0 + kr) * 8192 + sAc + tx];
    tb[kr][tx] = w[(size_t)(k0 + kr) * 8192 + sBc + tx];
  }
  __syncthreads();
  {
    const int cc = tid >> 6;
    const int uu = tid & 63;
    const float cA0 = 0.5f * px_cA0[p], cA1 = 0.5f * px_cA1[p];
    const float cB0 = 0.5f * px_cB0[p], cB1 = 0.5f * px_cB1[p];
    float eA[8], eB[8];
#pragma unroll
    for (int q = 0; q < 8; ++q) {
      const float a = ta[cc * 8 + q][uu], b = tb[cc * 8 + q][uu];
      eA[q] = cA0 * a + cA1 * b;
      eB[q] = cB0 * a + cB1 * b;
    }
    uint4 oA, oB;
    oA.x = pk2(eA[0], eA[1]); oA.y = pk2(eA[2], eA[3]);
    oA.z = pk2(eA[4], eA[5]); oA.w = pk2(eA[6], eA[7]);
    oB.x = pk2(eB[0], eB[1]); oB.y = pk2(eB[2], eB[3]);
    oB.z = pk2(eB[4], eB[5]); oB.w = pk2(eB[6], eB[7]);
    const size_t off = (size_t)(blockIdx.y * 4 + cc) * 1024 + nb * 64 + uu;
    wv[(size_t)px_vA[p] * 131072 + off] = oA;
    wv[(size_t)px_vB[p] * 131072 + off] = oB;
  }
}

// bias prefill (atomic path only)
__global__ void bias_fill(const float* __restrict__ bias, float4* __restrict__ out) {
  int idx = blockIdx.x * 256 + threadIdx.x;
  int row = idx >> 8;
  int c4 = idx & 255;
  int k = row >> 9;
  out[idx] = ((const float4*)(bias + k * UQ))[c4];
}

// 2-way merge (44 MB path)
__global__ void merge_kernel(float* out, const float* __restrict__ part,
                             const float* __restrict__ bias) {
  const int q4 = blockIdx.x * 256 + threadIdx.x;
  f32x4* o4 = (f32x4*)out;
  const f32x4* p4 = (const f32x4*)part;
  const f32x4* b4 = (const f32x4*)bias;
  f32x4 P[8];
#pragma unroll
  for (int d = 0; d < 8; ++d)
    P[d] = o4[d * 131072 + q4] + p4[d * 131072 + q4];
  const int u4 = q4 & 255;
  o4[0 * 131072 + q4] = P[0] + P[6] + b4[0 * 256 + u4];
  o4[1 * 131072 + q4] = P[2] + P[4] + b4[1 * 256 + u4];
  o4[2 * 131072 + q4] = P[5] - P[3] + b4[2 * 256 + u4];
  o4[3 * 131072 + q4] = P[0] - P[6] + b4[3 * 256 + u4];
  o4[4 * 131072 + q4] = P[1] - P[7] + b4[4 * 256 + u4];
  o4[5 * 131072 + q4] = P[4] - P[2] + b4[5 * 256 + u4];
  o4[6 * 131072 + q4] = P[3] + P[5] + b4[6 * 256 + u4];
  o4[7 * 131072 + q4] = P[1] + P[7] + b4[7 * 256 + u4];
}

// 4-way merge (76 MB path)
__global__ void merge4_kernel(float* out, const float* __restrict__ pt,
                              const float* __restrict__ bias) {
  const int q4 = blockIdx.x * 256 + threadIdx.x;
  f32x4* o4 = (f32x4*)out;
  const f32x4* p1 = (const f32x4*)pt;
  const f32x4* p2 = p1 + 1048576;
  const f32x4* p3 = p2 + 1048576;
  const f32x4* b4 = (const f32x4*)bias;
  f32x4 P[8];
#pragma unroll
  for (int d = 0; d < 8; ++d) {
    const size_t o = (size_t)d * 131072 + q4;
    P[d] = o4[o] + p1[o] + p2[o] + p3[o];
  }
  const int u4 = q4 & 255;
  o4[0 * 131072 + q4] = P[0] + P[6] + b4[0 * 256 + u4];
  o4[1 * 131072 + q4] = P[2] + P[4] + b4[1 * 256 + u4];
  o4[2 * 131072 + q4] = P[5] - P[3] + b4[2 * 256 + u4];
  o4[3 * 131072 + q4] = P[0] - P[6] + b4[3 * 256 + u4];
  o4[4 * 131072 + q4] = P[1] - P[7] + b4[4 * 256 + u4];
  o4[5 * 131072 + q4] = P[4] - P[2] + b4[5 * 256 + u4];
  o4[6 * 131072 + q4] = P[3] + P[5] + b4[6 * 256 + u4];
  o4[7 * 131072 + q4] = P[1] + P[7] + b4[7 * 256 + u4];
}

#define BAR() do { asm volatile("s_barrier" ::: "memory");                    \
                   __builtin_amdgcn_sched_barrier(0); } while (0)
#define VMW(N) asm volatile("s_waitcnt vmcnt(" #N ")" ::: "memory")

// ---- NEW: 256x128 tile, split-K=4, ring-3, 2 blocks/CU ----
// Wave tile 128x64 (2x2 waves): LDS traffic 34.3 B/MFLOP vs 45.7 at 128^2
// (A staged 16K read 2x, B staged 8K read 2x = 72 KB per 2.1 MFLOP-iter).
// Ring-3 x 24 KB = 72 KB LDS -> 2 blocks/CU. Ledger: 6 loads/stage;
// stage(t+2) -> slot (t+2)%3 (consumed at t-1, cross-wave safe via BAR);
// VMW(6) at iter top forces stage(t) landed; never drains to 0.
__global__ __launch_bounds__(256, 2) void ga_split4(
    const uint16_t* __restrict__ xv, const uint16_t* __restrict__ wv,
    float* __restrict__ out, float* __restrict__ part) {
  __shared__ uint16_t lds[3][12288];  // [slot][A 8192 | B 4096] = 72 KB

  const int tid  = threadIdx.x;
  const int bid  = blockIdx.x;
  const int s    = bid >> 7;          // split 0..3 (= segment index)
  const int d    = (bid >> 4) & 7;    // dest
  const int mt   = (bid >> 3) & 1;    // 256-row tile
  const int ut   = bid & 7;           // 128-col tile
  const int lane = tid & 63;
  const int wid  = tid >> 6;
  const int wr   = wid >> 1, wc = wid & 1;  // 2x2 waves, wave = 128x64
  const int r15  = lane & 15, hi = lane >> 4;

  const uint16_t* aB = xv + (size_t)c_sa[d][s] * 524288;
  const uint16_t* bB = wv + (size_t)c_sb[d][s] * 1048576;

  f32x4 acc[8][4];
  const f32x4 z = {0.f, 0.f, 0.f, 0.f};
#pragma unroll
  for (int a = 0; a < 8; ++a)
#pragma unroll
    for (int b = 0; b < 4; ++b) acc[a][b] = z;

  // stage iter u (4 chunks = K32): A 4 loads + B 2 loads per thread
  auto stage = [&](int u) {
    const int c0 = u << 2;
    uint16_t* la = lds[u % 3];
    uint16_t* lb = lds[u % 3] + 8192;
#pragma unroll
    for (int r = 0; r < 4; ++r) {
      const int e = r * 256 + tid;          // 0..1023: chunk e>>8, row e&255
      __builtin_amdgcn_global_load_lds(
          (const __attribute__((address_space(1))) uint32_t*)
              (aB + ((size_t)(c0 + (e >> 8)) * 512 + mt * 256 + (e & 255)) * 8),
          (__attribute__((address_space(3))) uint32_t*)(la + e * 8), 16, 0, 0);
    }
#pragma unroll
    for (int r = 0; r < 2; ++r) {
      const int e = r * 256 + tid;          // 0..511: chunk e>>7, col e&127
      __builtin_amdgcn_global_load_lds(
          (const __attribute__((address_space(1))) uint32_t*)
              (bB + ((size_t)(c0 + (e >> 7)) * 1024 + ut * 128 + (e & 127)) * 8),
          (__attribute__((address_space(3))) uint32_t*)(lb + e * 8), 16, 0, 0);
    }
  };

  stage(0); stage(1);

  for (int t = 0; t < 32; ++t) {
    VMW(6);   // forces stage(t) landed (only stage(t+1)'s 6 outstanding)
    BAR();
    stage((t + 2 < 32) ? t + 2 : 31);       // tail dup = same bytes, benign
    const uint16_t* L = lds[t % 3];
    bf16x8 af[8], bf[4];
#pragma unroll
    for (int f = 0; f < 8; ++f)
      af[f] = *(const bf16x8*)(L + ((hi << 8) + wr * 128 + f * 16 + r15) * 8);
#pragma unroll
    for (int g = 0; g < 4; ++g)
      bf[g] = *(const bf16x8*)(L + 8192 + ((hi << 7) + wc * 64 + g * 16 + r15) * 8);
    __builtin_amdgcn_sched_barrier(0);
#pragma unroll
    for (int f = 0; f < 8; ++f)
#pragma unroll
      for (int g = 0; g < 4; ++g)
        acc[f][g] = __builtin_amdgcn_mfma_f32_16x16x32_bf16(
            af[f], bf[g], acc[f][g], 0, 0, 0);
  }

  // epilogue: plain-store into split-s buffer (dest-major)
  float* dst = ((s == 0) ? out : part + (size_t)(s - 1) * 4194304) +
               (size_t)d * 524288;
  const int row0 = mt * 256 + wr * 128;
  const int col0 = ut * 128 + wc * 64;
#pragma unroll
  for (int g = 0; g < 4; ++g) {
    const int col = col0 + g * 16 + r15;
#pragma unroll
    for (int f = 0; f < 8; ++f) {
      const int r0 = row0 + f * 16 + hi * 4;
#pragma unroll
      for (int r = 0; r < 4; ++r)
        dst[(size_t)(r0 + r) * UQ + col] = acc[f][g][r];
    }
  }
}

// ---- R15 kernel (44 MB / 28 MB fallback paths), unchanged ----
template<int ATOMIC>
__global__ __launch_bounds__(256, 2) void ga_cplx(
    const uint16_t* __restrict__ xv, const uint16_t* __restrict__ wv,
    float* __restrict__ out, float* __restrict__ part) {
  __shared__ uint16_t lds[4][8192];

  const int tid  = threadIdx.x;
  const int bid  = blockIdx.x;
  const int s    = bid >> 8;
  const int d    = (bid >> 5) & 7;
  const int mt   = (bid >> 3) & 3;
  const int ut   = bid & 7;
  const int lane = tid & 63;
  const int wid  = tid >> 6;
  const int wr   = wid >> 1, wc = wid & 1;
  const int r15  = lane & 15, hi = lane >> 4;

  const uint16_t* aB0 = xv + (size_t)c_sa[d][s * 2 + 0] * 524288;
  const uint16_t* aB1 = xv + (size_t)c_sa[d][s * 2 + 1] * 524288;
  const uint16_t* bB0 = wv + (size_t)c_sb[d][s * 2 + 0] * 1048576;
  const uint16_t* bB1 = wv + (size_t)c_sb[d][s * 2 + 1] * 1048576;

  const int hc = tid >> 7;
  const size_t mrow8 = (size_t)(mt * 128 + (tid & 127)) * 8;
  const size_t urow8 = (size_t)(ut * 128 + (tid & 127)) * 8;

  f32x4 acc[4][4];
  const f32x4 z = {0.f, 0.f, 0.f, 0.f};
#pragma unroll
  for (int a = 0; a < 4; ++a)
#pragma unroll
    for (int b = 0; b < 4; ++b) acc[a][b] = z;

  auto stage = [&](int u) {
    const uint16_t* pa = (u & 32) ? aB1 : aB0;
    const uint16_t* pb = (u & 32) ? bB1 : bB0;
    const int c0 = (u & 31) << 2;
    uint16_t* la = lds[u & 3];
    uint16_t* lb = lds[u & 3] + 4096;
#pragma unroll
    for (int u2 = 0; u2 < 2; ++u2) {
      const int cc = c0 + u2 * 2 + hc;
      __builtin_amdgcn_global_load_lds(
          (const __attribute__((address_space(1))) uint32_t*)(pa + (size_t)cc * 4096 + mrow8),
          (__attribute__((address_space(3))) uint32_t*)(la + (u2 * 256 + tid) * 8), 16, 0, 0);
      __builtin_amdgcn_global_load_lds(
          (const __attribute__((address_space(1))) uint32_t*)(pb + (size_t)cc * 8192 + urow8),
          (__attribute__((address_space(3))) uint32_t*)(lb + (u2 * 256 + tid) * 8), 16, 0, 0);
    }
  };

#define READF(FA, FB, RB) {                                                   \
  const uint16_t* b_ = lds[(RB)];                                             \
  _Pragma("unroll")                                                           \
  for (int f = 0; f < 4; ++f)                                                 \
    FA[f] = *(const bf16x8*)(b_ + ((hi << 7) + wr * 64 + f * 16 + r15) * 8);  \
  _Pragma("unroll")                                                           \
  for (int g = 0; g < 4; ++g)                                                 \
    FB[g] = *(const bf16x8*)(b_ + 4096 + ((hi << 7) + wc * 64 + g * 16 + r15) * 8); \
}

#define KEEP(FA, FB)                                                          \
  asm volatile("" : "+v"(FA[0]), "+v"(FA[1]), "+v"(FA[2]), "+v"(FA[3]),       \
                    "+v"(FB[0]), "+v"(FB[1]), "+v"(FB[2]), "+v"(FB[3]));

#define MFMA16(CA, CB) {                                                      \
  _Pragma("unroll")                                                           \
  for (int f = 0; f < 4; ++f)                                                 \
    _Pragma("unroll")                                                         \
    for (int g = 0; g < 4; ++g)                                               \
      acc[f][g] = __builtin_amdgcn_mfma_f32_16x16x32_bf16(                    \
          CA[f], CB[g], acc[f][g], 0, 0, 0);                                  \
}

#define ITER(T, CA, CB, LA, LB) {                                             \
  VMW(4);                                                                     \
  BAR();                                                                      \
  stage(((T) + 3 < 63) ? (T) + 3 : 63);                                       \
  READF(LA, LB, ((((T) + 1 < 63) ? (T) + 1 : 63) & 3));                       \
  __builtin_amdgcn_sched_barrier(0);                                          \
  MFMA16(CA, CB);                                                             \
  __builtin_amdgcn_sched_barrier(0);                                          \
  KEEP(LA, LB);                                                               \
}

  bf16x8 fCa[4], fCb[4], fNa[4], fNb[4];

  stage(0); stage(1); stage(2);
  VMW(4);
  BAR();
  READF(fCa, fCb, 0);
  KEEP(fCa, fCb);

  for (int t = 0; t < 64; t += 2) {
    ITER(t,     fCa, fCb, fNa, fNb);
    ITER(t + 1, fNa, fNb, fCa, fCb);
  }

  const int row0 = mt * 128 + wr * 64;
  const int col0 = ut * 128 + wc * 64;
  if constexpr (ATOMIC) {
    const int rb0 = c_eb0[d], rb1 = c_eb1[d];
    const float es0 = c_es0[d], es1 = c_es1[d];
#pragma unroll
    for (int g = 0; g < 4; ++g) {
      const int col = col0 + g * 16 + r15;
#pragma unroll
      for (int f = 0; f < 4; ++f) {
        const int r0 = row0 + f * 16 + hi * 4;
#pragma unroll
        for (int r = 0; r < 4; ++r) {
          const float val = acc[f][g][r];
          unsafeAtomicAdd(&out[(size_t)(rb0 * MBS + r0 + r) * UQ + col], es0 * val);
          unsafeAtomicAdd(&out[(size_t)(rb1 * MBS + r0 + r) * UQ + col], es1 * val);
        }
      }
    }
  } else {
    float* dst = (s ? part : out) + (size_t)d * 524288;
#pragma unroll
    for (int g = 0; g < 4; ++g) {
      const int col = col0 + g * 16 + r15;
#pragma unroll
      for (int f = 0; f < 4; ++f) {
        const int r0 = row0 + f * 16 + hi * 4;
#pragma unroll
        for (int r = 0; r < 4; ++r)
          dst[(size_t)(r0 + r) * UQ + col] = acc[f][g][r];
      }
    }
  }
}

// Fallback (ws too small): correct fp32 path, slow.
__global__ void ga_naive(const float* __restrict__ x, const float* __restrict__ w,
                         const float* __restrict__ bias, float* __restrict__ out) {
  int col = blockIdx.x * 256 + threadIdx.x;
  int row = blockIdx.y;
  int k = row >> 9, m = row & 511;
  float acc = bias[k * UQ + col];
  for (int i = 0; i < 8; ++i) {
    int j = c_sigma[i][k];
    float s = (float)c_sg[i][k];
    const float* xr = x + (size_t)(i * MBS + m) * CIN;
    const float* wc = w + (size_t)j * UQ + col;
    float a = 0.f;
    for (int c = 0; c < CIN; ++c) a = fmaf(xr[c], wc[(size_t)c * (NBL * UQ)], a);
    acc = fmaf(s, a, acc);
  }
  out[(size_t)row * UQ + col] = acc;
}

extern "C" void kernel_launch(void* const* d_in, const int* in_sizes, int n_in,
                              void* d_out, int out_size, void* d_ws, size_t ws_size,
                              hipStream_t stream) {
  const float* x    = (const float*)d_in[0];   // 4096*1024
  const float* W    = (const float*)d_in[1];   // 1024*8192
  const float* bias = (const float*)d_in[2];   // 8192
  float* out = (float*)d_out;                  // 4096*1024

  const size_t needC = 79691776u;              // Xv 12 + Wv 16 + 3 parts 48
  const size_t needA = 44u * 1024u * 1024u;    // Xv 12 + Wv 16 + 1 part 16
  const size_t needB = 28u * 1024u * 1024u;    // Xv 12 + Wv 16
  if (ws_size < needB) {
    ga_naive<<<dim3(4, 4096), dim3(256), 0, stream>>>(x, W, bias, out);
    return;
  }

  uint16_t* xv = (uint16_t*)d_ws;              // 12 * 524288 u16
  uint16_t* wv = xv + 6291456;                 // 8 * 1048576 u16
  float* part  = (float*)((char*)d_ws + 29360128);

  cvt_x_kernel<<<dim3(16, 16), dim3(256), 0, stream>>>(x, (uint4*)xv);
  cvt_w_kernel<<<dim3(64, 32), dim3(256), 0, stream>>>(W, (uint4*)wv);

  if (ws_size >= needC) {
    ga_split4<<<dim3(512), dim3(256), 0, stream>>>(xv, wv, out, part);
    merge4_kernel<<<dim3(512), dim3(256), 0, stream>>>(out, part, bias);
  } else if (ws_size >= needA) {
    ga_cplx<0><<<dim3(512), dim3(256), 0, stream>>>(xv, wv, out, part);
    merge_kernel<<<dim3(512), dim3(256), 0, stream>>>(out, part, bias);
  } else {
    bias_fill<<<dim3(4096), dim3(256), 0, stream>>>(bias, (float4*)out);
    ga_cplx<1><<<dim3(512), dim3(256), 0, stream>>>(xv, wv, out, nullptr);
  }
}

// Round 18
// 64.083 us; speedup vs baseline: 1.1421x; 1.1421x over previous
//
#include <hip/hip_runtime.h>
#include <stdint.h>

#define NBL 8
#define MBS 512
#define CIN 1024
#define UQ  1024

// ---- Cl(3,0) ~ M2(C) tables (HW-verified R11/R12) ----
__device__ __constant__ int   px_sA[4] = {0,1,4,2};
__device__ __constant__ int   px_sB[4] = {3,5,7,6};
__device__ __constant__ int   px_vA[4] = {0,1,4,5};
__device__ __constant__ float px_cA0[4] = {1,1,1,-1};
__device__ __constant__ float px_cA1[4] = {1,-1,1,1};
__device__ __constant__ int   px_vB[4] = {3,2,7,6};
__device__ __constant__ float px_cB0[4] = {1,1,-1,1};
__device__ __constant__ float px_cB1[4] = {-1,1,1,1};
__device__ __constant__ int c_sa[8][4] = {
  {0,8,1,9},{0,4,1,5},{0,8,1,9},{0,4,1,5},
  {2,10,3,11},{2,6,3,7},{2,10,3,11},{2,6,3,7}};
__device__ __constant__ int c_sb[8][4] = {
  {0,4,2,6},{4,0,6,2},{1,5,3,7},{5,1,7,3},
  {0,4,2,6},{4,0,6,2},{1,5,3,7},{5,1,7,3}};
// dest -> two blade outputs (atomic fallback path)
__device__ __constant__ int   c_eb0[8] = {0,4,1,2,1,2,0,4};
__device__ __constant__ float c_es0[8] = {1,1,1,-1,1,1,1,-1};
__device__ __constant__ int   c_eb1[8] = {3,7,5,6,5,6,3,7};
__device__ __constant__ float c_es1[8] = {1,1,-1,1,1,1,-1,1};

// original Cayley tables (naive fallback only)
__device__ __constant__ int c_sigma[8][8] = {
  {0,1,2,3,4,5,6,7},{1,0,4,5,2,3,7,6},{2,4,0,6,1,7,3,5},{3,5,6,0,7,1,2,4},
  {4,2,1,7,0,6,5,3},{5,3,7,1,6,0,4,2},{6,7,3,2,5,4,0,1},{7,6,5,4,3,2,1,0}};
__device__ __constant__ int c_sg[8][8] = {
  {1,1,1,1,1,1,1,1},{1,1,1,1,1,1,1,1},{1,-1,1,1,-1,-1,1,-1},{1,-1,-1,1,1,-1,-1,1},
  {-1,1,-1,-1,1,1,-1,1},{-1,1,1,-1,-1,1,1,-1},{-1,-1,1,-1,1,-1,1,1},{-1,-1,1,-1,1,-1,1,1}};

typedef short bf16x8 __attribute__((ext_vector_type(8)));
typedef float f32x4 __attribute__((ext_vector_type(4)));

__device__ __forceinline__ uint32_t f2bf(float f) {
  uint32_t u = __float_as_uint(f);
  return (u + 0x7fffu + ((u >> 16) & 1u)) >> 16;  // RNE
}
__device__ __forceinline__ uint32_t pk2(float lo, float hi) {
  return f2bf(lo) | (f2bf(hi) << 16);
}

// Xv[v 0..11][chunk 0..127][row 0..511][8] bf16, pair-shared sources.
__global__ void cvt_x_kernel(const float* __restrict__ x, uint4* __restrict__ xv) {
  __shared__ uint4 tA[32 * 33], tB[32 * 33];
  const int tid = threadIdx.x;           // 256
  const int tx = tid & 31, ty = tid >> 5;
  const int p  = blockIdx.x >> 2;        // pair 0..3
  const int cb = blockIdx.x & 3;
  const int m0 = blockIdx.y * 32;
  const int sA = px_sA[p] * MBS, sB = px_sB[p] * MBS;
  const float cA0 = px_cA0[p], cA1 = px_cA1[p];
  const float cB0 = px_cB0[p], cB1 = px_cB1[p];
#pragma unroll
  for (int r = 0; r < 4; ++r) {
    const int m = m0 + ty + r * 8;
    const float* pa = x + (size_t)(sA + m) * CIN + cb * 256 + tx * 8;
    const float* pb = x + (size_t)(sB + m) * CIN + cb * 256 + tx * 8;
    float4 a0 = *(const float4*)pa, a1 = *(const float4*)(pa + 4);
    float4 b0 = *(const float4*)pb, b1 = *(const float4*)(pb + 4);
    uint4 vA, vB;
    vA.x = pk2(cA0*a0.x + cA1*b0.x, cA0*a0.y + cA1*b0.y);
    vA.y = pk2(cA0*a0.z + cA1*b0.z, cA0*a0.w + cA1*b0.w);
    vA.z = pk2(cA0*a1.x + cA1*b1.x, cA0*a1.y + cA1*b1.y);
    vA.w = pk2(cA0*a1.z + cA1*b1.z, cA0*a1.w + cA1*b1.w);
    vB.x = pk2(cB0*a0.x + cB1*b0.x, cB0*a0.y + cB1*b0.y);
    vB.y = pk2(cB0*a0.z + cB1*b0.z, cB0*a0.w + cB1*b0.w);
    vB.z = pk2(cB0*a1.x + cB1*b1.x, cB0*a1.y + cB1*b1.y);
    vB.w = pk2(cB0*a1.z + cB1*b1.z, cB0*a1.w + cB1*b1.w);
    tA[tx * 33 + ty + r * 8] = vA;
    tB[tx * 33 + ty + r * 8] = vB;
  }
  __syncthreads();
  const int vA = px_vA[p], vB = px_vB[p];
#pragma unroll
  for (int ph = 0; ph < 4; ++ph) {
    const int slot = ph * 256 + tid;
    const int cc = slot >> 5, mm = slot & 31;
    const size_t off = (size_t)(cb * 32 + cc) * 512 + m0 + mm;
    uint4 a = tA[cc * 33 + mm];
    uint4 b = tB[cc * 33 + mm];
    xv[(size_t)vA * 65536 + off] = a;
    xv[(size_t)vB * 65536 + off] = b;
    if (p >= 2) {
      uint4 na, nb;
      na.x = a.x ^ 0x80008000u; na.y = a.y ^ 0x80008000u;
      na.z = a.z ^ 0x80008000u; na.w = a.w ^ 0x80008000u;
      nb.x = b.x ^ 0x80008000u; nb.y = b.y ^ 0x80008000u;
      nb.z = b.z ^ 0x80008000u; nb.w = b.w ^ 0x80008000u;
      xv[(size_t)(vA + 4) * 65536 + off] = na;
      xv[(size_t)(vB + 4) * 65536 + off] = nb;
    }
  }
}

// Wv[v 0..7][chunk 0..127][col 0..1023][8] bf16, scaled 0.5, pair-shared.
__global__ void cvt_w_kernel(const float* __restrict__ w, uint4* __restrict__ wv) {
  __shared__ float ta[32][65], tb[32][65];
  const int tid = threadIdx.x;  // 256
  const int tx = tid & 63, ty = tid >> 6;
  const int p  = blockIdx.x >> 4;
  const int nb = blockIdx.x & 15;
  const int k0 = blockIdx.y * 32;
  const int sAc = px_sA[p] * UQ + nb * 64;
  const int sBc = px_sB[p] * UQ + nb * 64;
#pragma unroll
  for (int r = 0; r < 8; ++r) {
    const int kr = ty * 8 + r;
    ta[kr][tx] = w[(size_t)(k0 + kr) * 8192 + sAc + tx];
    tb[kr][tx] = w[(size_t)(k0 + kr) * 8192 + sBc + tx];
  }
  __syncthreads();
  {
    const int cc = tid >> 6;
    const int uu = tid & 63;
    const float cA0 = 0.5f * px_cA0[p], cA1 = 0.5f * px_cA1[p];
    const float cB0 = 0.5f * px_cB0[p], cB1 = 0.5f * px_cB1[p];
    float eA[8], eB[8];
#pragma unroll
    for (int q = 0; q < 8; ++q) {
      const float a = ta[cc * 8 + q][uu], b = tb[cc * 8 + q][uu];
      eA[q] = cA0 * a + cA1 * b;
      eB[q] = cB0 * a + cB1 * b;
    }
    uint4 oA, oB;
    oA.x = pk2(eA[0], eA[1]); oA.y = pk2(eA[2], eA[3]);
    oA.z = pk2(eA[4], eA[5]); oA.w = pk2(eA[6], eA[7]);
    oB.x = pk2(eB[0], eB[1]); oB.y = pk2(eB[2], eB[3]);
    oB.z = pk2(eB[4], eB[5]); oB.w = pk2(eB[6], eB[7]);
    const size_t off = (size_t)(blockIdx.y * 4 + cc) * 1024 + nb * 64 + uu;
    wv[(size_t)px_vA[p] * 131072 + off] = oA;
    wv[(size_t)px_vB[p] * 131072 + off] = oB;
  }
}

// bias prefill (atomic path only)
__global__ void bias_fill(const float* __restrict__ bias, float4* __restrict__ out) {
  int idx = blockIdx.x * 256 + threadIdx.x;
  int row = idx >> 8;
  int c4 = idx & 255;
  int k = row >> 9;
  out[idx] = ((const float4*)(bias + k * UQ))[c4];
}

// merge: out (dest-major split0) + part (split1) -> blade outputs in place.
__global__ void merge_kernel(float* out, const float* __restrict__ part,
                             const float* __restrict__ bias) {
  const int q4 = blockIdx.x * 256 + threadIdx.x;   // 0..131071
  f32x4* o4 = (f32x4*)out;
  const f32x4* p4 = (const f32x4*)part;
  const f32x4* b4 = (const f32x4*)bias;
  f32x4 P[8];
#pragma unroll
  for (int d = 0; d < 8; ++d)
    P[d] = o4[d * 131072 + q4] + p4[d * 131072 + q4];
  const int u4 = q4 & 255;
  o4[0 * 131072 + q4] = P[0] + P[6] + b4[0 * 256 + u4];
  o4[1 * 131072 + q4] = P[2] + P[4] + b4[1 * 256 + u4];
  o4[2 * 131072 + q4] = P[5] - P[3] + b4[2 * 256 + u4];
  o4[3 * 131072 + q4] = P[0] - P[6] + b4[3 * 256 + u4];
  o4[4 * 131072 + q4] = P[1] - P[7] + b4[4 * 256 + u4];
  o4[5 * 131072 + q4] = P[4] - P[2] + b4[5 * 256 + u4];
  o4[6 * 131072 + q4] = P[3] + P[5] + b4[6 * 256 + u4];
  o4[7 * 131072 + q4] = P[1] + P[7] + b4[7 * 256 + u4];
}

#define BAR() do { asm volatile("s_barrier" ::: "memory");                    \
                   __builtin_amdgcn_sched_barrier(0); } while (0)
#define VMW(N) asm volatile("s_waitcnt vmcnt(" #N ")" ::: "memory")

// ---- complex-block GEMM, split-K=2, ring-4, frag dbuf + XCD swizzle ----
// T1: wgid = (bid%8)*64 + bid/8 (bijective, 512%8==0). Each XCD's 64
// co-resident blocks then cover only 2 (s,d) groups (12 MB of panels,
// marched in lockstep K-order) -> staging delivery comes from L2 instead
// of streaming 512 MB from L3 (R15 measured 13.1 TB/s delivery = L3-class).
template<int ATOMIC>
__global__ __launch_bounds__(256, 2) void ga_cplx(
    const uint16_t* __restrict__ xv, const uint16_t* __restrict__ wv,
    float* __restrict__ out, float* __restrict__ part) {
  __shared__ uint16_t lds[4][8192];  // ring: [buf][A 4096 | B 4096] = 64 KB

  const int tid  = threadIdx.x;
  const int bid  = blockIdx.x;
  const int wgid = ((bid & 7) << 6) + (bid >> 3);  // XCD-aware remap
  const int s    = wgid >> 8;          // K-split 0/1
  const int d    = (wgid >> 5) & 7;    // dest O-block
  const int mt   = (wgid >> 3) & 3;
  const int ut   = wgid & 7;
  const int lane = tid & 63;
  const int wid  = tid >> 6;
  const int wr   = wid >> 1, wc = wid & 1;
  const int r15  = lane & 15, hi = lane >> 4;

  const uint16_t* aB0 = xv + (size_t)c_sa[d][s * 2 + 0] * 524288;
  const uint16_t* aB1 = xv + (size_t)c_sa[d][s * 2 + 1] * 524288;
  const uint16_t* bB0 = wv + (size_t)c_sb[d][s * 2 + 0] * 1048576;
  const uint16_t* bB1 = wv + (size_t)c_sb[d][s * 2 + 1] * 1048576;

  const int hc = tid >> 7;
  const size_t mrow8 = (size_t)(mt * 128 + (tid & 127)) * 8;
  const size_t urow8 = (size_t)(ut * 128 + (tid & 127)) * 8;

  f32x4 acc[4][4];
  const f32x4 z = {0.f, 0.f, 0.f, 0.f};
#pragma unroll
  for (int a = 0; a < 4; ++a)
#pragma unroll
    for (int b = 0; b < 4; ++b) acc[a][b] = z;

  auto stage = [&](int u) {
    const uint16_t* pa = (u & 32) ? aB1 : aB0;
    const uint16_t* pb = (u & 32) ? bB1 : bB0;
    const int c0 = (u & 31) << 2;
    uint16_t* la = lds[u & 3];
    uint16_t* lb = lds[u & 3] + 4096;
#pragma unroll
    for (int u2 = 0; u2 < 2; ++u2) {
      const int cc = c0 + u2 * 2 + hc;
      __builtin_amdgcn_global_load_lds(
          (const __attribute__((address_space(1))) uint32_t*)(pa + (size_t)cc * 4096 + mrow8),
          (__attribute__((address_space(3))) uint32_t*)(la + (u2 * 256 + tid) * 8), 16, 0, 0);
      __builtin_amdgcn_global_load_lds(
          (const __attribute__((address_space(1))) uint32_t*)(pb + (size_t)cc * 8192 + urow8),
          (__attribute__((address_space(3))) uint32_t*)(lb + (u2 * 256 + tid) * 8), 16, 0, 0);
    }
  };

#define READF(FA, FB, RB) {                                                   \
  const uint16_t* b_ = lds[(RB)];                                             \
  _Pragma("unroll")                                                           \
  for (int f = 0; f < 4; ++f)                                                 \
    FA[f] = *(const bf16x8*)(b_ + ((hi << 7) + wr * 64 + f * 16 + r15) * 8);  \
  _Pragma("unroll")                                                           \
  for (int g = 0; g < 4; ++g)                                                 \
    FB[g] = *(const bf16x8*)(b_ + 4096 + ((hi << 7) + wc * 64 + g * 16 + r15) * 8); \
}

#define KEEP(FA, FB)                                                          \
  asm volatile("" : "+v"(FA[0]), "+v"(FA[1]), "+v"(FA[2]), "+v"(FA[3]),       \
                    "+v"(FB[0]), "+v"(FB[1]), "+v"(FB[2]), "+v"(FB[3]));

#define MFMA16(CA, CB) {                                                      \
  _Pragma("unroll")                                                           \
  for (int f = 0; f < 4; ++f)                                                 \
    _Pragma("unroll")                                                         \
    for (int g = 0; g < 4; ++g)                                               \
      acc[f][g] = __builtin_amdgcn_mfma_f32_16x16x32_bf16(                    \
          CA[f], CB[g], acc[f][g], 0, 0, 0);                                  \
}

#define ITER(T, CA, CB, LA, LB) {                                             \
  VMW(4);                                                                     \
  BAR();                                                                      \
  stage(((T) + 3 < 63) ? (T) + 3 : 63);                                       \
  READF(LA, LB, ((((T) + 1 < 63) ? (T) + 1 : 63) & 3));                       \
  __builtin_amdgcn_sched_barrier(0);                                          \
  MFMA16(CA, CB);                                                             \
  __builtin_amdgcn_sched_barrier(0);                                          \
  KEEP(LA, LB);                                                               \
}

  bf16x8 fCa[4], fCb[4], fNa[4], fNb[4];

  stage(0); stage(1); stage(2);
  VMW(4);
  BAR();
  READF(fCa, fCb, 0);
  KEEP(fCa, fCb);

  for (int t = 0; t < 64; t += 2) {
    ITER(t,     fCa, fCb, fNa, fNb);
    ITER(t + 1, fNa, fNb, fCa, fCb);
  }

  const int row0 = mt * 128 + wr * 64;
  const int col0 = ut * 128 + wc * 64;
  if constexpr (ATOMIC) {
    const int rb0 = c_eb0[d], rb1 = c_eb1[d];
    const float es0 = c_es0[d], es1 = c_es1[d];
#pragma unroll
    for (int g = 0; g < 4; ++g) {
      const int col = col0 + g * 16 + r15;
#pragma unroll
      for (int f = 0; f < 4; ++f) {
        const int r0 = row0 + f * 16 + hi * 4;
#pragma unroll
        for (int r = 0; r < 4; ++r) {
          const float val = acc[f][g][r];
          unsafeAtomicAdd(&out[(size_t)(rb0 * MBS + r0 + r) * UQ + col], es0 * val);
          unsafeAtomicAdd(&out[(size_t)(rb1 * MBS + r0 + r) * UQ + col], es1 * val);
        }
      }
    }
  } else {
    float* dst = (s ? part : out) + (size_t)d * 524288;
#pragma unroll
    for (int g = 0; g < 4; ++g) {
      const int col = col0 + g * 16 + r15;
#pragma unroll
      for (int f = 0; f < 4; ++f) {
        const int r0 = row0 + f * 16 + hi * 4;
#pragma unroll
        for (int r = 0; r < 4; ++r)
          dst[(size_t)(r0 + r) * UQ + col] = acc[f][g][r];
      }
    }
  }
}

// Fallback (ws too small): correct fp32 path, slow.
__global__ void ga_naive(const float* __restrict__ x, const float* __restrict__ w,
                         const float* __restrict__ bias, float* __restrict__ out) {
  int col = blockIdx.x * 256 + threadIdx.x;
  int row = blockIdx.y;
  int k = row >> 9, m = row & 511;
  float acc = bias[k * UQ + col];
  for (int i = 0; i < 8; ++i) {
    int j = c_sigma[i][k];
    float s = (float)c_sg[i][k];
    const float* xr = x + (size_t)(i * MBS + m) * CIN;
    const float* wc = w + (size_t)j * UQ + col;
    float a = 0.f;
    for (int c = 0; c < CIN; ++c) a = fmaf(xr[c], wc[(size_t)c * (NBL * UQ)], a);
    acc = fmaf(s, a, acc);
  }
  out[(size_t)row * UQ + col] = acc;
}

extern "C" void kernel_launch(void* const* d_in, const int* in_sizes, int n_in,
                              void* d_out, int out_size, void* d_ws, size_t ws_size,
                              hipStream_t stream) {
  const float* x    = (const float*)d_in[0];   // 4096*1024
  const float* W    = (const float*)d_in[1];   // 1024*8192
  const float* bias = (const float*)d_in[2];   // 8192
  float* out = (float*)d_out;                  // 4096*1024

  const size_t needA = 44u * 1024u * 1024u;    // Xv 12 + Wv 16 + part 16
  const size_t needB = 28u * 1024u * 1024u;    // Xv 12 + Wv 16
  if (ws_size < needB) {
    ga_naive<<<dim3(4, 4096), dim3(256), 0, stream>>>(x, W, bias, out);
    return;
  }

  uint16_t* xv = (uint16_t*)d_ws;              // 12 * 524288 u16
  uint16_t* wv = xv + 6291456;                 // 8 * 1048576 u16
  float* part  = (float*)((char*)d_ws + 29360128);  // 16 MB partials

  cvt_x_kernel<<<dim3(16, 16), dim3(256), 0, stream>>>(x, (uint4*)xv);
  cvt_w_kernel<<<dim3(64, 32), dim3(256), 0, stream>>>(W, (uint4*)wv);

  if (ws_size >= needA) {
    ga_cplx<0><<<dim3(512), dim3(256), 0, stream>>>(xv, wv, out, part);
    merge_kernel<<<dim3(512), dim3(256), 0, stream>>>(out, part, bias);
  } else {
    bias_fill<<<dim3(4096), dim3(256), 0, stream>>>(bias, (float4*)out);
    ga_cplx<1><<<dim3(512), dim3(256), 0, stream>>>(xv, wv, out, nullptr);
  }
}

// Round 19
// 64.022 us; speedup vs baseline: 1.1432x; 1.0009x over previous
//
#include <hip/hip_runtime.h>
#include <stdint.h>

#define NBL 8
#define MBS 512
#define CIN 1024
#define UQ  1024

// ---- Cl(3,0) ~ M2(C) tables (HW-verified R11/R12) ----
__device__ __constant__ int   px_sA[4] = {0,1,4,2};
__device__ __constant__ int   px_sB[4] = {3,5,7,6};
__device__ __constant__ int   px_vA[4] = {0,1,4,5};
__device__ __constant__ float px_cA0[4] = {1,1,1,-1};
__device__ __constant__ float px_cA1[4] = {1,-1,1,1};
__device__ __constant__ int   px_vB[4] = {3,2,7,6};
__device__ __constant__ float px_cB0[4] = {1,1,-1,1};
__device__ __constant__ float px_cB1[4] = {-1,1,1,1};
__device__ __constant__ int c_sa[8][4] = {
  {0,8,1,9},{0,4,1,5},{0,8,1,9},{0,4,1,5},
  {2,10,3,11},{2,6,3,7},{2,10,3,11},{2,6,3,7}};
__device__ __constant__ int c_sb[8][4] = {
  {0,4,2,6},{4,0,6,2},{1,5,3,7},{5,1,7,3},
  {0,4,2,6},{4,0,6,2},{1,5,3,7},{5,1,7,3}};
// dest -> two blade outputs (atomic fallback path)
__device__ __constant__ int   c_eb0[8] = {0,4,1,2,1,2,0,4};
__device__ __constant__ float c_es0[8] = {1,1,1,-1,1,1,1,-1};
__device__ __constant__ int   c_eb1[8] = {3,7,5,6,5,6,3,7};
__device__ __constant__ float c_es1[8] = {1,1,-1,1,1,1,-1,1};

// original Cayley tables (naive fallback only)
__device__ __constant__ int c_sigma[8][8] = {
  {0,1,2,3,4,5,6,7},{1,0,4,5,2,3,7,6},{2,4,0,6,1,7,3,5},{3,5,6,0,7,1,2,4},
  {4,2,1,7,0,6,5,3},{5,3,7,1,6,0,4,2},{6,7,3,2,5,4,0,1},{7,6,5,4,3,2,1,0}};
__device__ __constant__ int c_sg[8][8] = {
  {1,1,1,1,1,1,1,1},{1,1,1,1,1,1,1,1},{1,-1,1,1,-1,-1,1,-1},{1,-1,-1,1,1,-1,-1,1},
  {-1,1,-1,-1,1,1,-1,1},{-1,1,1,-1,-1,1,1,-1},{-1,-1,1,-1,1,-1,1,1},{-1,-1,1,-1,1,-1,1,1}};

typedef short bf16x8 __attribute__((ext_vector_type(8)));
typedef float f32x4 __attribute__((ext_vector_type(4)));

__device__ __forceinline__ uint32_t f2bf(float f) {
  uint32_t u = __float_as_uint(f);
  return (u + 0x7fffu + ((u >> 16) & 1u)) >> 16;  // RNE
}
__device__ __forceinline__ uint32_t pk2(float lo, float hi) {
  return f2bf(lo) | (f2bf(hi) << 16);
}

// Xv[v 0..11][chunk 0..127][row 0..511][8] bf16, pair-shared sources.
__global__ void cvt_x_kernel(const float* __restrict__ x, uint4* __restrict__ xv) {
  __shared__ uint4 tA[32 * 33], tB[32 * 33];
  const int tid = threadIdx.x;           // 256
  const int tx = tid & 31, ty = tid >> 5;
  const int p  = blockIdx.x >> 2;        // pair 0..3
  const int cb = blockIdx.x & 3;
  const int m0 = blockIdx.y * 32;
  const int sA = px_sA[p] * MBS, sB = px_sB[p] * MBS;
  const float cA0 = px_cA0[p], cA1 = px_cA1[p];
  const float cB0 = px_cB0[p], cB1 = px_cB1[p];
#pragma unroll
  for (int r = 0; r < 4; ++r) {
    const int m = m0 + ty + r * 8;
    const float* pa = x + (size_t)(sA + m) * CIN + cb * 256 + tx * 8;
    const float* pb = x + (size_t)(sB + m) * CIN + cb * 256 + tx * 8;
    float4 a0 = *(const float4*)pa, a1 = *(const float4*)(pa + 4);
    float4 b0 = *(const float4*)pb, b1 = *(const float4*)(pb + 4);
    uint4 vA, vB;
    vA.x = pk2(cA0*a0.x + cA1*b0.x, cA0*a0.y + cA1*b0.y);
    vA.y = pk2(cA0*a0.z + cA1*b0.z, cA0*a0.w + cA1*b0.w);
    vA.z = pk2(cA0*a1.x + cA1*b1.x, cA0*a1.y + cA1*b1.y);
    vA.w = pk2(cA0*a1.z + cA1*b1.z, cA0*a1.w + cA1*b1.w);
    vB.x = pk2(cB0*a0.x + cB1*b0.x, cB0*a0.y + cB1*b0.y);
    vB.y = pk2(cB0*a0.z + cB1*b0.z, cB0*a0.w + cB1*b0.w);
    vB.z = pk2(cB0*a1.x + cB1*b1.x, cB0*a1.y + cB1*b1.y);
    vB.w = pk2(cB0*a1.z + cB1*b1.z, cB0*a1.w + cB1*b1.w);
    tA[tx * 33 + ty + r * 8] = vA;
    tB[tx * 33 + ty + r * 8] = vB;
  }
  __syncthreads();
  const int vA = px_vA[p], vB = px_vB[p];
#pragma unroll
  for (int ph = 0; ph < 4; ++ph) {
    const int slot = ph * 256 + tid;
    const int cc = slot >> 5, mm = slot & 31;
    const size_t off = (size_t)(cb * 32 + cc) * 512 + m0 + mm;
    uint4 a = tA[cc * 33 + mm];
    uint4 b = tB[cc * 33 + mm];
    xv[(size_t)vA * 65536 + off] = a;
    xv[(size_t)vB * 65536 + off] = b;
    if (p >= 2) {
      uint4 na, nb;
      na.x = a.x ^ 0x80008000u; na.y = a.y ^ 0x80008000u;
      na.z = a.z ^ 0x80008000u; na.w = a.w ^ 0x80008000u;
      nb.x = b.x ^ 0x80008000u; nb.y = b.y ^ 0x80008000u;
      nb.z = b.z ^ 0x80008000u; nb.w = b.w ^ 0x80008000u;
      xv[(size_t)(vA + 4) * 65536 + off] = na;
      xv[(size_t)(vB + 4) * 65536 + off] = nb;
    }
  }
}

// Wv[v 0..7][chunk 0..127][col 0..1023][8] bf16, scaled 0.5, pair-shared.
__global__ void cvt_w_kernel(const float* __restrict__ w, uint4* __restrict__ wv) {
  __shared__ float ta[32][65], tb[32][65];
  const int tid = threadIdx.x;  // 256
  const int tx = tid & 63, ty = tid >> 6;
  const int p  = blockIdx.x >> 4;
  const int nb = blockIdx.x & 15;
  const int k0 = blockIdx.y * 32;
  const int sAc = px_sA[p] * UQ + nb * 64;
  const int sBc = px_sB[p] * UQ + nb * 64;
#pragma unroll
  for (int r = 0; r < 8; ++r) {
    const int kr = ty * 8 + r;
    ta[kr][tx] = w[(size_t)(k0 + kr) * 8192 + sAc + tx];
    tb[kr][tx] = w[(size_t)(k0 + kr) * 8192 + sBc + tx];
  }
  __syncthreads();
  {
    const int cc = tid >> 6;
    const int uu = tid & 63;
    const float cA0 = 0.5f * px_cA0[p], cA1 = 0.5f * px_cA1[p];
    const float cB0 = 0.5f * px_cB0[p], cB1 = 0.5f * px_cB1[p];
    float eA[8], eB[8];
#pragma unroll
    for (int q = 0; q < 8; ++q) {
      const float a = ta[cc * 8 + q][uu], b = tb[cc * 8 + q][uu];
      eA[q] = cA0 * a + cA1 * b;
      eB[q] = cB0 * a + cB1 * b;
    }
    uint4 oA, oB;
    oA.x = pk2(eA[0], eA[1]); oA.y = pk2(eA[2], eA[3]);
    oA.z = pk2(eA[4], eA[5]); oA.w = pk2(eA[6], eA[7]);
    oB.x = pk2(eB[0], eB[1]); oB.y = pk2(eB[2], eB[3]);
    oB.z = pk2(eB[4], eB[5]); oB.w = pk2(eB[6], eB[7]);
    const size_t off = (size_t)(blockIdx.y * 4 + cc) * 1024 + nb * 64 + uu;
    wv[(size_t)px_vA[p] * 131072 + off] = oA;
    wv[(size_t)px_vB[p] * 131072 + off] = oB;
  }
}

// bias prefill (atomic path only)
__global__ void bias_fill(const float* __restrict__ bias, float4* __restrict__ out) {
  int idx = blockIdx.x * 256 + threadIdx.x;
  int row = idx >> 8;
  int c4 = idx & 255;
  int k = row >> 9;
  out[idx] = ((const float4*)(bias + k * UQ))[c4];
}

// merge: out (dest-major split0) + part (split1) -> blade outputs in place.
__global__ void merge_kernel(float* out, const float* __restrict__ part,
                             const float* __restrict__ bias) {
  const int q4 = blockIdx.x * 256 + threadIdx.x;   // 0..131071
  f32x4* o4 = (f32x4*)out;
  const f32x4* p4 = (const f32x4*)part;
  const f32x4* b4 = (const f32x4*)bias;
  f32x4 P[8];
#pragma unroll
  for (int d = 0; d < 8; ++d)
    P[d] = o4[d * 131072 + q4] + p4[d * 131072 + q4];
  const int u4 = q4 & 255;
  o4[0 * 131072 + q4] = P[0] + P[6] + b4[0 * 256 + u4];
  o4[1 * 131072 + q4] = P[2] + P[4] + b4[1 * 256 + u4];
  o4[2 * 131072 + q4] = P[5] - P[3] + b4[2 * 256 + u4];
  o4[3 * 131072 + q4] = P[0] - P[6] + b4[3 * 256 + u4];
  o4[4 * 131072 + q4] = P[1] - P[7] + b4[4 * 256 + u4];
  o4[5 * 131072 + q4] = P[4] - P[2] + b4[5 * 256 + u4];
  o4[6 * 131072 + q4] = P[3] + P[5] + b4[6 * 256 + u4];
  o4[7 * 131072 + q4] = P[1] + P[7] + b4[7 * 256 + u4];
}

#define BAR() do { asm volatile("s_barrier" ::: "memory");                    \
                   __builtin_amdgcn_sched_barrier(0); } while (0)
#define VMW(N) asm volatile("s_waitcnt vmcnt(" #N ")" ::: "memory")

// ---- complex-block GEMM, split-K=2, ring-4, READ-AHEAD DEPTH 2 ----
// MFMA(t) consumes frags read at iter t-2 (retired a full iter ago), so the
// compiler's lgkm wait before MFMA is trivially satisfied and iter-t's 8
// ds_reads retire UNDER iter-t's MFMA cluster. 4 named frag buffers
// (static idx), loop unrolled x4. Ledger: stage(t+4) -> slot t&3 (its regs
// consumed by READF(t) at iter t-2, done); VMW(4) at iter top proves
// stage(t+2) landed for READF(t+2). Tail clamps dup-stage/read slot 63
// (identical bytes / dead regs -> benign).
template<int ATOMIC>
__global__ __launch_bounds__(256, 2) void ga_cplx(
    const uint16_t* __restrict__ xv, const uint16_t* __restrict__ wv,
    float* __restrict__ out, float* __restrict__ part) {
  __shared__ uint16_t lds[4][8192];  // ring: [buf][A 4096 | B 4096] = 64 KB

  const int tid  = threadIdx.x;
  const int bid  = blockIdx.x;
  const int s    = bid >> 8;          // K-split 0/1
  const int d    = (bid >> 5) & 7;    // dest O-block
  const int mt   = (bid >> 3) & 3;
  const int ut   = bid & 7;
  const int lane = tid & 63;
  const int wid  = tid >> 6;
  const int wr   = wid >> 1, wc = wid & 1;
  const int r15  = lane & 15, hi = lane >> 4;

  const uint16_t* aB0 = xv + (size_t)c_sa[d][s * 2 + 0] * 524288;
  const uint16_t* aB1 = xv + (size_t)c_sa[d][s * 2 + 1] * 524288;
  const uint16_t* bB0 = wv + (size_t)c_sb[d][s * 2 + 0] * 1048576;
  const uint16_t* bB1 = wv + (size_t)c_sb[d][s * 2 + 1] * 1048576;

  const int hc = tid >> 7;
  const size_t mrow8 = (size_t)(mt * 128 + (tid & 127)) * 8;
  const size_t urow8 = (size_t)(ut * 128 + (tid & 127)) * 8;

  f32x4 acc[4][4];
  const f32x4 z = {0.f, 0.f, 0.f, 0.f};
#pragma unroll
  for (int a = 0; a < 4; ++a)
#pragma unroll
    for (int b = 0; b < 4; ++b) acc[a][b] = z;

  auto stage = [&](int u) {
    const uint16_t* pa = (u & 32) ? aB1 : aB0;
    const uint16_t* pb = (u & 32) ? bB1 : bB0;
    const int c0 = (u & 31) << 2;
    uint16_t* la = lds[u & 3];
    uint16_t* lb = lds[u & 3] + 4096;
#pragma unroll
    for (int u2 = 0; u2 < 2; ++u2) {
      const int cc = c0 + u2 * 2 + hc;
      __builtin_amdgcn_global_load_lds(
          (const __attribute__((address_space(1))) uint32_t*)(pa + (size_t)cc * 4096 + mrow8),
          (__attribute__((address_space(3))) uint32_t*)(la + (u2 * 256 + tid) * 8), 16, 0, 0);
      __builtin_amdgcn_global_load_lds(
          (const __attribute__((address_space(1))) uint32_t*)(pb + (size_t)cc * 8192 + urow8),
          (__attribute__((address_space(3))) uint32_t*)(lb + (u2 * 256 + tid) * 8), 16, 0, 0);
    }
  };

#define READF(FA, FB, RB) {                                                   \
  const uint16_t* b_ = lds[(RB)];                                             \
  _Pragma("unroll")                                                           \
  for (int f = 0; f < 4; ++f)                                                 \
    FA[f] = *(const bf16x8*)(b_ + ((hi << 7) + wr * 64 + f * 16 + r15) * 8);  \
  _Pragma("unroll")                                                           \
  for (int g = 0; g < 4; ++g)                                                 \
    FB[g] = *(const bf16x8*)(b_ + 4096 + ((hi << 7) + wc * 64 + g * 16 + r15) * 8); \
}

#define KEEP(FA, FB)                                                          \
  asm volatile("" : "+v"(FA[0]), "+v"(FA[1]), "+v"(FA[2]), "+v"(FA[3]),       \
                    "+v"(FB[0]), "+v"(FB[1]), "+v"(FB[2]), "+v"(FB[3]));

#define MFMA16(CA, CB) {                                                      \
  _Pragma("unroll")                                                           \
  for (int f = 0; f < 4; ++f)                                                 \
    _Pragma("unroll")                                                         \
    for (int g = 0; g < 4; ++g)                                               \
      acc[f][g] = __builtin_amdgcn_mfma_f32_16x16x32_bf16(                    \
          CA[f], CB[g], acc[f][g], 0, 0, 0);                                  \
}

// iter T: consume buf[T&3]; read buf[(T+2)&3] from ring slot (T+2)&3;
// stage(T+4) into slot T&3.
#define ITER(T, CA, CB, LA, LB) {                                             \
  VMW(4);                                                                     \
  BAR();                                                                      \
  stage(((T) + 4 < 63) ? (T) + 4 : 63);                                       \
  READF(LA, LB, ((((T) + 2 < 63) ? (T) + 2 : 63) & 3));                       \
  __builtin_amdgcn_sched_barrier(0);                                          \
  MFMA16(CA, CB);                                                             \
  __builtin_amdgcn_sched_barrier(0);                                          \
  KEEP(LA, LB);                                                               \
}

  bf16x8 f0a[4], f0b[4], f1a[4], f1b[4], f2a[4], f2b[4], f3a[4], f3b[4];

  // prologue: stage 0..3 (16 loads); VMW(8) -> 0,1 landed; pre-read bufs 0,1
  stage(0); stage(1); stage(2); stage(3);
  VMW(8);
  BAR();
  READF(f0a, f0b, 0);
  READF(f1a, f1b, 1);
  KEEP(f0a, f0b);
  KEEP(f1a, f1b);

  for (int t = 0; t < 64; t += 4) {
    ITER(t,     f0a, f0b, f2a, f2b);
    ITER(t + 1, f1a, f1b, f3a, f3b);
    ITER(t + 2, f2a, f2b, f0a, f0b);
    ITER(t + 3, f3a, f3b, f1a, f1b);
  }

  const int row0 = mt * 128 + wr * 64;
  const int col0 = ut * 128 + wc * 64;
  if constexpr (ATOMIC) {
    const int rb0 = c_eb0[d], rb1 = c_eb1[d];
    const float es0 = c_es0[d], es1 = c_es1[d];
#pragma unroll
    for (int g = 0; g < 4; ++g) {
      const int col = col0 + g * 16 + r15;
#pragma unroll
      for (int f = 0; f < 4; ++f) {
        const int r0 = row0 + f * 16 + hi * 4;
#pragma unroll
        for (int r = 0; r < 4; ++r) {
          const float val = acc[f][g][r];
          unsafeAtomicAdd(&out[(size_t)(rb0 * MBS + r0 + r) * UQ + col], es0 * val);
          unsafeAtomicAdd(&out[(size_t)(rb1 * MBS + r0 + r) * UQ + col], es1 * val);
        }
      }
    }
  } else {
    float* dst = (s ? part : out) + (size_t)d * 524288;
#pragma unroll
    for (int g = 0; g < 4; ++g) {
      const int col = col0 + g * 16 + r15;
#pragma unroll
      for (int f = 0; f < 4; ++f) {
        const int r0 = row0 + f * 16 + hi * 4;
#pragma unroll
        for (int r = 0; r < 4; ++r)
          dst[(size_t)(r0 + r) * UQ + col] = acc[f][g][r];
      }
    }
  }
}

// Fallback (ws too small): correct fp32 path, slow.
__global__ void ga_naive(const float* __restrict__ x, const float* __restrict__ w,
                         const float* __restrict__ bias, float* __restrict__ out) {
  int col = blockIdx.x * 256 + threadIdx.x;
  int row = blockIdx.y;
  int k = row >> 9, m = row & 511;
  float acc = bias[k * UQ + col];
  for (int i = 0; i < 8; ++i) {
    int j = c_sigma[i][k];
    float s = (float)c_sg[i][k];
    const float* xr = x + (size_t)(i * MBS + m) * CIN;
    const float* wc = w + (size_t)j * UQ + col;
    float a = 0.f;
    for (int c = 0; c < CIN; ++c) a = fmaf(xr[c], wc[(size_t)c * (NBL * UQ)], a);
    acc = fmaf(s, a, acc);
  }
  out[(size_t)row * UQ + col] = acc;
}

extern "C" void kernel_launch(void* const* d_in, const int* in_sizes, int n_in,
                              void* d_out, int out_size, void* d_ws, size_t ws_size,
                              hipStream_t stream) {
  const float* x    = (const float*)d_in[0];   // 4096*1024
  const float* W    = (const float*)d_in[1];   // 1024*8192
  const float* bias = (const float*)d_in[2];   // 8192
  float* out = (float*)d_out;                  // 4096*1024

  const size_t needA = 44u * 1024u * 1024u;    // Xv 12 + Wv 16 + part 16
  const size_t needB = 28u * 1024u * 1024u;    // Xv 12 + Wv 16
  if (ws_size < needB) {
    ga_naive<<<dim3(4, 4096), dim3(256), 0, stream>>>(x, W, bias, out);
    return;
  }

  uint16_t* xv = (uint16_t*)d_ws;              // 12 * 524288 u16
  uint16_t* wv = xv + 6291456;                 // 8 * 1048576 u16
  float* part  = (float*)((char*)d_ws + 29360128);  // 16 MB partials

  cvt_x_kernel<<<dim3(16, 16), dim3(256), 0, stream>>>(x, (uint4*)xv);
  cvt_w_kernel<<<dim3(64, 32), dim3(256), 0, stream>>>(W, (uint4*)wv);

  if (ws_size >= needA) {
    ga_cplx<0><<<dim3(512), dim3(256), 0, stream>>>(xv, wv, out, part);
    merge_kernel<<<dim3(512), dim3(256), 0, stream>>>(out, part, bias);
  } else {
    bias_fill<<<dim3(4096), dim3(256), 0, stream>>>(bias, (float4*)out);
    ga_cplx<1><<<dim3(512), dim3(256), 0, stream>>>(xv, wv, out, nullptr);
  }
}